// Round 6
// baseline (2436.827 us; speedup 1.0000x reference)
//
#include <hip/hip_runtime.h>

#define EPS 1e-6f

constexpr int N_ = 8;
constexpr int H_ = 720;
constexpr int W_ = 1280;
constexpr int HW = H_ * W_;
constexpr int NPIX = N_ * HW;        // 7,372,800  (= 28800 blocks * 256)

// Native no-return HW fp atomic: global_atomic_add_f32 (memory-side add,
// fire-and-forget). NOT the CAS retry loop that plain atomicAdd() lowers to,
// and no sc0/return -> no line-ownership round trip in the dep chain.
__device__ __forceinline__ void fadd_native(float* p, float v) {
    unsafeAtomicAdd(p, v);
}

// ---------------------------------------------------------------------------
// Single-kernel splat: one thread per source pixel, 4 native global fadd
// pairs into the two d_out accumulator planes.
//
// XCD slab swizzle: grid is 28800 blocks = 8 images x 3600 blocks. Dispatch
// assigns blocks round-robin across the 8 XCDs, so b -> (b&7)*3600 + (b>>3)
// gives XCD k exclusively image k: every atomic target line is shared only
// within one XCD -> stays resident in that XCD's 4 MiB L2 (live band is
// ~50 rows ~ 0.5 MB). Perf heuristic only; correctness is mapping-agnostic.
// ---------------------------------------------------------------------------
__global__ __launch_bounds__(256) void splat_global_kernel(
        const float* __restrict__ img,
        const float* __restrict__ counts,
        const float* __restrict__ flo,
        float* __restrict__ acc_img,     // d_out plane 0
        float* __restrict__ acc_one) {   // d_out plane 1
    int b  = blockIdx.x;
    int bs = (b & 7) * (gridDim.x >> 3) + (b >> 3);   // XCD slab swizzle
    int idx = bs * 256 + threadIdx.x;
    if (idx >= NPIX) return;

    int w = idx % W_;
    int t = idx / W_;
    int h = t % H_;
    int n = t / H_;

    float iv = img[idx];
    float cv = counts[idx];
    int fbase = ((n * 2) * H_ + h) * W_ + w;
    float y = flo[fbase];                // channel 0 shifts W axis
    float x = flo[fbase + HW];           // channel 1 shifts H axis

    float x1 = floorf(x);
    float y1 = floorf(y);
    float fx = x - x1, fy = y - y1;
    float gx = 1.0f - fx, gy = 1.0f - fy;
    float ex1 = __expf(-fx * fx), ex2 = __expf(-gx * gx);
    float ey1 = __expf(-fy * fy), ey2 = __expf(-gy * gy);
    float s = (ex1 + ex2) * (ey1 + ey2);
    float inv = cv / s;

    int ix1 = (int)x1 + h, ix2 = ix1 + 1;
    int iy1 = (int)y1 + w, iy2 = iy1 + 1;
    int nbase = n * HW;

    bool vx1 = (unsigned)ix1 < (unsigned)H_;
    bool vx2 = (unsigned)ix2 < (unsigned)H_;
    bool vy1 = (unsigned)iy1 < (unsigned)W_;
    bool vy2 = (unsigned)iy2 < (unsigned)W_;

    if (vx1 && vy1) {
        int o = nbase + ix1 * W_ + iy1; float ww = ex1 * ey1 * inv;
        fadd_native(acc_img + o, iv * ww); fadd_native(acc_one + o, ww);
    }
    if (vx1 && vy2) {
        int o = nbase + ix1 * W_ + iy2; float ww = ex1 * ey2 * inv;
        fadd_native(acc_img + o, iv * ww); fadd_native(acc_one + o, ww);
    }
    if (vx2 && vy1) {
        int o = nbase + ix2 * W_ + iy1; float ww = ex2 * ey1 * inv;
        fadd_native(acc_img + o, iv * ww); fadd_native(acc_one + o, ww);
    }
    if (vx2 && vy2) {
        int o = nbase + ix2 * W_ + iy2; float ww = ex2 * ey2 * inv;
        fadd_native(acc_img + o, iv * ww); fadd_native(acc_one + o, ww);
    }
}

// ---------------------------------------------------------------------------
// Finalize: out0 = acc0 / (acc1 + eps), out1 = acc1 (in place), float4-wide.
// NPIX % 4 == 0.
// ---------------------------------------------------------------------------
__global__ __launch_bounds__(256) void finalize4_kernel(
        float* __restrict__ out0,
        const float* __restrict__ out1) {
    int i = blockIdx.x * blockDim.x + threadIdx.x;
    if (i >= NPIX / 4) return;
    float4 a = ((const float4*)out0)[i];
    float4 o = ((const float4*)out1)[i];
    a.x = a.x / (o.x + EPS);
    a.y = a.y / (o.y + EPS);
    a.z = a.z / (o.z + EPS);
    a.w = a.w / (o.w + EPS);
    ((float4*)out0)[i] = a;
}

extern "C" void kernel_launch(void* const* d_in, const int* in_sizes, int n_in,
                              void* d_out, int out_size, void* d_ws, size_t ws_size,
                              hipStream_t stream) {
    const float* img    = (const float*)d_in[0];
    const float* counts = (const float*)d_in[1];
    const float* flo    = (const float*)d_in[2];

    float* out0 = (float*)d_out;
    float* out1 = out0 + NPIX;

    // d_out is re-poisoned to 0xAA before every timed call; both planes are
    // the atomic accumulators -> zero them.
    (void)hipMemsetAsync(d_out, 0, (size_t)2 * NPIX * sizeof(float), stream);

    const int threads = 256;
    const int blocks = NPIX / threads;               // 28800, divisible by 8
    splat_global_kernel<<<blocks, threads, 0, stream>>>(img, counts, flo,
                                                        out0, out1);
    finalize4_kernel<<<(NPIX / 4 + threads - 1) / threads, threads, 0, stream>>>(
        out0, out1);
}